// Round 13
// baseline (1457.594 us; speedup 1.0000x reference)
//
#include <hip/hip_runtime.h>
#include <cmath>

#define NHEAD 12
#define NTOK 49
#define CDIM 768
#define C2DIM 384
#define HDIM 64
#define HD2 32
#define TSEL 32
#define BATCH 2048
#define MROWS (BATCH * NTOK)   // 100352
#define MVROWS (BATCH * TSEL)  // 65536
constexpr float SCALE_Q = 0.125f; // 64^-0.5

typedef _Float16 f16x8 __attribute__((ext_vector_type(8)));
typedef _Float16 f16x4 __attribute__((ext_vector_type(4)));
typedef _Float16 f16x2 __attribute__((ext_vector_type(2)));
typedef float f32x4 __attribute__((ext_vector_type(4)));

// fp16 2-limb split: x == hi + lo + O(2^-24 x)
__device__ __forceinline__ void split8(const float* v, f16x8& hi, f16x8& lo) {
    #pragma unroll
    for (int u = 0; u < 8; ++u) {
        const _Float16 h = (_Float16)v[u];
        hi[u] = h;
        lo[u] = (_Float16)(v[u] - (float)h);
    }
}
__device__ __forceinline__ void round8h(const float* v, f16x8& h) {
    #pragma unroll
    for (int u = 0; u < 8; ++u) h[u] = (_Float16)v[u];
}
// XOR-swizzled granule index (involution; conflict-free proven R5-R12)
#define GIX(g) ((g) ^ ((((g) >> 7) & 3) << 1))

// ---------------------------------------------------------------------------
// q GEMM (R10-R12 proven, 430 us): reg-staged 128x128 / 4-wave / BK=32
// fp16x3 split loop + fused-stats epilogue.  __launch_bounds__(256,2).
// ---------------------------------------------------------------------------
__global__ __launch_bounds__(256, 2) void gemm_q_kernel(
    const float* __restrict__ A, const float* __restrict__ W,
    const float* __restrict__ bias, _Float16* __restrict__ Cq,
    float* __restrict__ rowmean, float* __restrict__ psumA,
    float* __restrict__ pmaxA)
{
    const int K = CDIM;
    __shared__ f16x8 AhiS[512], AloS[512], BhiS[512], BloS[512]; // 32 KB
    const int tid = threadIdx.x;
    const int lane = tid & 63, wid = tid >> 6;
    const int wr = wid >> 1, wc = wid & 1;
    const int g4 = lane >> 4, l15 = lane & 15;
    const int rsub = tid >> 2, kc = tid & 3;
    const int bid = blockIdx.x;                 // 4704 = 8 * 588
    const int vv = (bid & 7) * 588 + (bid >> 3);
    const int bx = vv / 6, by = vv % 6;
    const int mBase = bx * 128, nBase = by * 128;

    f32x4 acc[4][4] = {};

    for (int kt = 0; kt < K; kt += 32) {
        __syncthreads();
        #pragma unroll
        for (int pass = 0; pass < 2; ++pass) {
            const int row = rsub + pass * 64;
            const int g = kc * 128 + row;
            const int gi = GIX(g);
            {
                const float* ap = &A[(size_t)(mBase + row) * K + kt + kc * 8];
                float av[8];
                *reinterpret_cast<float4*>(&av[0]) = *reinterpret_cast<const float4*>(ap);
                *reinterpret_cast<float4*>(&av[4]) = *reinterpret_cast<const float4*>(ap + 4);
                f16x8 h, l; split8(av, h, l);
                AhiS[gi] = h; AloS[gi] = l;
            }
            {
                const float* wp = &W[(size_t)(nBase + row) * K + kt + kc * 8];
                float wv[8];
                *reinterpret_cast<float4*>(&wv[0]) = *reinterpret_cast<const float4*>(wp);
                *reinterpret_cast<float4*>(&wv[4]) = *reinterpret_cast<const float4*>(wp + 4);
                f16x8 h, l; split8(wv, h, l);
                BhiS[gi] = h; BloS[gi] = l;
            }
        }
        __syncthreads();

        const int ksl = g4 << 7;
        f16x8 ah[4], al[4], bh[4], bl[4];
        #pragma unroll
        for (int f = 0; f < 4; ++f) {
            ah[f] = AhiS[GIX(ksl + wr * 64 + f * 16 + l15)];
            al[f] = AloS[GIX(ksl + wr * 64 + f * 16 + l15)];
            bh[f] = BhiS[GIX(ksl + wc * 64 + f * 16 + l15)];
            bl[f] = BloS[GIX(ksl + wc * 64 + f * 16 + l15)];
        }
        #pragma unroll
        for (int i = 0; i < 4; ++i)
            #pragma unroll
            for (int j = 0; j < 4; ++j) {
                acc[i][j] = __builtin_amdgcn_mfma_f32_16x16x32_f16(ah[i], bh[j], acc[i][j], 0, 0, 0);
                acc[i][j] = __builtin_amdgcn_mfma_f32_16x16x32_f16(ah[i], bl[j], acc[i][j], 0, 0, 0);
                acc[i][j] = __builtin_amdgcn_mfma_f32_16x16x32_f16(al[i], bh[j], acc[i][j], 0, 0, 0);
            }
    }

    const int head = by * 2 + wc;

    // ---- C write (fp16, + bias)
    #pragma unroll
    for (int i = 0; i < 4; ++i) {
        #pragma unroll
        for (int j = 0; j < 4; ++j) {
            const int col = nBase + wc * 64 + j * 16 + l15;
            const float bv = bias[col];
            #pragma unroll
            for (int r = 0; r < 4; ++r) {
                const int rowg = mBase + wr * 64 + i * 16 + g4 * 4 + r;
                Cq[(size_t)rowg * CDIM + col] = (_Float16)(acc[i][j][r] + bv);
            }
        }
    }

    // ---- rowmean (exact, deterministic) over this wave's 64 head cols
    float bsum = 0.f;
    #pragma unroll
    for (int j = 0; j < 4; ++j) bsum += bias[nBase + wc * 64 + j * 16 + l15];
    #pragma unroll
    for (int off = 1; off < 16; off <<= 1) bsum += __shfl_xor(bsum, off);

    const int R0 = mBase + wr * 64;
    #pragma unroll
    for (int i = 0; i < 4; ++i) {
        #pragma unroll
        for (int r = 0; r < 4; ++r) {
            float s = acc[i][0][r] + acc[i][1][r] + acc[i][2][r] + acc[i][3][r];
            #pragma unroll
            for (int off = 1; off < 16; off <<= 1) s += __shfl_xor(s, off);
            if (l15 == 0)
                rowmean[(size_t)(R0 + i * 16 + g4 * 4 + r) * NHEAD + head] =
                    (s + bsum) * (1.0f / 64.0f);
        }
    }

    // ---- channel sum/max partials per 64-row window segment
    const int bS = R0 / NTOK, bE = (R0 + 63) / NTOK;
    for (int b = bS; b <= bE; ++b) {
        const int lo = (49 * b > R0 ? 49 * b - R0 : 0);
        const int hiB = 49 * b + 49;
        const int hi = (hiB < R0 + 64 ? hiB - R0 : 64);
        float ps[4] = {0.f, 0.f, 0.f, 0.f};
        float pm[4] = {-INFINITY, -INFINITY, -INFINITY, -INFINITY};
        #pragma unroll
        for (int i = 0; i < 4; ++i) {
            #pragma unroll
            for (int r = 0; r < 4; ++r) {
                const int rl_ = i * 16 + g4 * 4 + r;
                if (rl_ >= lo && rl_ < hi) {
                    #pragma unroll
                    for (int j = 0; j < 4; ++j) {
                        ps[j] += acc[i][j][r];
                        pm[j] = fmaxf(pm[j], acc[i][j][r]);
                    }
                }
            }
        }
        #pragma unroll
        for (int j = 0; j < 4; ++j) {
            ps[j] += __shfl_xor(ps[j], 16);
            ps[j] += __shfl_xor(ps[j], 32);
            pm[j] = fmaxf(pm[j], __shfl_xor(pm[j], 16));
            pm[j] = fmaxf(pm[j], __shfl_xor(pm[j], 32));
        }
        const int which = (R0 >> 6) - ((49 * b) >> 6); // 0 or 1
        if (lane < 16) {
            #pragma unroll
            for (int j = 0; j < 4; ++j) {
                const int idx = ((b * 2 + which) * NHEAD + head) * 64 + j * 16 + lane;
                psumA[idx] = ps[j];
                pmaxA[idx] = pm[j];
            }
        }
    }
}

// ---------------------------------------------------------------------------
// Combine partials + top-k selections. Rank selection == lax.top_k + sort.
// ---------------------------------------------------------------------------
__global__ __launch_bounds__(64) void topk_kernel(
    const float* __restrict__ psumA, const float* __restrict__ pmaxA,
    const float* __restrict__ rowmean, const float* __restrict__ bq,
    const float* __restrict__ Wc, const float* __restrict__ bc,
    int* __restrict__ cidx, int* __restrict__ p)
{
    const int blk = blockIdx.x;
    const int b = blk / NHEAD, nh = blk % NHEAD;
    const int tid = threadIdx.x;

    __shared__ float chmean[64], chmax[64], rs[NTOK], logits[64];

    {
        const int i0 = ((b * 2 + 0) * NHEAD + nh) * 64 + tid;
        float s = psumA[i0];
        float m = pmaxA[i0];
        if (((49 * b) >> 6) != ((49 * b + 48) >> 6)) {
            const int i1 = ((b * 2 + 1) * NHEAD + nh) * 64 + tid;
            s += psumA[i1];
            m = fmaxf(m, pmaxA[i1]);
        }
        const float bqv = bq[nh * 64 + tid];
        chmean[tid] = s * (1.0f / 49.0f) + bqv;
        chmax[tid] = m + bqv;
    }
    if (tid < NTOK) rs[tid] = rowmean[(size_t)(b * NTOK + tid) * NHEAD + nh];
    __syncthreads();

    float accv = bc[tid];
    const float* wrow = Wc + tid * 128;
    for (int c = 0; c < 64; c++) accv += chmean[c] * wrow[c];
    for (int c = 0; c < 64; c++) accv += chmax[c] * wrow[64 + c];
    const float gl = 0.5f * accv * (1.0f + erff(accv * 0.70710678118654752f));
    logits[tid] = gl;
    __syncthreads();

    int rank = 0;
    for (int kk = 0; kk < 64; kk++) {
        const float o = logits[kk];
        rank += (o > gl) || (o == gl && kk < tid);
    }
    const bool sel = rank < HD2;
    const unsigned long long mask = __ballot(sel);
    if (sel) {
        const int pos = __popcll(mask & ((1ull << tid) - 1ull));
        cidx[blk * HD2 + pos] = tid;
    }
    __syncthreads();

    if (tid < NTOK) {
        const float rv = rs[tid];
        int rank2 = 0;
        for (int m = 0; m < NTOK; m++) {
            const float o = rs[m];
            rank2 += (o > rv) || (o == rv && m < tid);
        }
        const bool sel2 = rank2 < TSEL;
        const unsigned long long mask2 = __ballot(sel2);
        if (sel2) {
            const int pos = __popcll(mask2 & ((1ull << tid) - 1ull));
            p[blk * TSEL + pos] = tid;
        }
    }
}

// ---------------------------------------------------------------------------
// Reg-staged plain-fp16 GEMM, BK=64 (R11/R12 proven) with fp32 W rounded
// in-register during B staging (wconv kernels deleted; same RNE values).
// MODE 0: A = fp16 row-major (o buffer), fp32 output
// MODE 1: A = channel-gather from fp16 q (cidx), fp16 output (k)
// MODE 2: A = token-gather rows from fp16 q (pidx), fp16 output (v)
// ---------------------------------------------------------------------------
template <int MODE>
__global__ __launch_bounds__(256, 2) void gemm_f16_kernel(
    const void* __restrict__ Asrc, const float* __restrict__ Bw32,
    const float* __restrict__ bias, void* __restrict__ Cout,
    int N, int K, int PER, int F, const int* __restrict__ gidx)
{
    __shared__ f16x8 AS[1024], BS[1024]; // 32 KB
    const int tid = threadIdx.x;
    const int lane = tid & 63, wid = tid >> 6;
    const int wr = wid >> 1, wc = wid & 1;
    const int bid = blockIdx.x;
    const int vv = (bid & 7) * PER + (bid >> 3);
    const int mBase = (vv / F) * 128, nBase = (vv % F) * 128;
    const int rsub = tid >> 2, kc = tid & 3;

    f32x4 acc[4][4] = {};

    for (int kt = 0; kt < K; kt += 64) {
        __syncthreads();
        #pragma unroll
        for (int pass = 0; pass < 2; ++pass) {
            const int row = rsub + pass * 64;
            #pragma unroll
            for (int half = 0; half < 2; ++half) {
                const int ks = kc + half * 4;
                const int g = ks * 128 + row;
                const int gi = GIX(g);
                const int kg = kt + ks * 8;
                if (MODE == 0) {
                    const _Float16* ap = (const _Float16*)Asrc;
                    AS[gi] = *reinterpret_cast<const f16x8*>(
                        &ap[(size_t)(mBase + row) * K + kg]);
                } else if (MODE == 1) {
                    const _Float16* Q = (const _Float16*)Asrc;
                    const int gm = mBase + row;
                    const int b = gm / NTOK;
                    const int nh = kg >> 5;
                    const int* cp = &gidx[(b * NHEAD + nh) * HD2 + (kg & 31)];
                    const int4 c0 = *reinterpret_cast<const int4*>(cp);
                    const int4 c1 = *reinterpret_cast<const int4*>(cp + 4);
                    const _Float16* qp = &Q[(size_t)gm * CDIM + nh * HDIM];
                    f16x8 h;
                    h[0] = qp[c0.x]; h[1] = qp[c0.y]; h[2] = qp[c0.z]; h[3] = qp[c0.w];
                    h[4] = qp[c1.x]; h[5] = qp[c1.y]; h[6] = qp[c1.z]; h[7] = qp[c1.w];
                    AS[gi] = h;
                } else { // MODE 2
                    const _Float16* Q = (const _Float16*)Asrc;
                    const int gm = mBase + row;
                    const int b = gm >> 5, t = gm & 31;
                    const int nh = kg >> 6;
                    const int row2 = gidx[(b * NHEAD + nh) * TSEL + t];
                    AS[gi] = *reinterpret_cast<const f16x8*>(
                        &Q[(size_t)(b * NTOK + row2) * CDIM + kg]);
                }
                {
                    const float* wp = &Bw32[(size_t)(nBase + row) * K + kg];
                    float wv[8];
                    *reinterpret_cast<float4*>(&wv[0]) = *reinterpret_cast<const float4*>(wp);
                    *reinterpret_cast<float4*>(&wv[4]) = *reinterpret_cast<const float4*>(wp + 4);
                    f16x8 h; round8h(wv, h);
                    BS[gi] = h;
                }
            }
        }
        __syncthreads();

        const int rl = lane & 15;
        #pragma unroll
        for (int half = 0; half < 2; ++half) {
            const int ksl = ((lane >> 4) + half * 4) << 7;
            f16x8 af[4], bf[4];
            #pragma unroll
            for (int f = 0; f < 4; ++f) {
                af[f] = AS[GIX(ksl + wr * 64 + f * 16 + rl)];
                bf[f] = BS[GIX(ksl + wc * 64 + f * 16 + rl)];
            }
            #pragma unroll
            for (int i = 0; i < 4; ++i)
                #pragma unroll
                for (int j = 0; j < 4; ++j)
                    acc[i][j] = __builtin_amdgcn_mfma_f32_16x16x32_f16(af[i], bf[j], acc[i][j], 0, 0, 0);
        }
    }

    #pragma unroll
    for (int i = 0; i < 4; ++i) {
        const int rbase = mBase + wr * 64 + i * 16 + ((lane >> 4) << 2);
        #pragma unroll
        for (int j = 0; j < 4; ++j) {
            const int col = nBase + wc * 64 + j * 16 + (lane & 15);
            const float bv = bias[col];
            #pragma unroll
            for (int r = 0; r < 4; ++r) {
                const float o = acc[i][j][r] + bv;
                if (MODE == 0)
                    ((float*)Cout)[(size_t)(rbase + r) * N + col] = o;
                else
                    ((_Float16*)Cout)[(size_t)(rbase + r) * N + col] = (_Float16)o;
            }
        }
    }
}

// ---------------------------------------------------------------------------
// Attention: 2 (b,nh) pairs per 256-thread block (structure proven R8;
// per-pair numerics identical to R12's vectorized + parallel-softmax kernel).
// ---------------------------------------------------------------------------
__global__ __launch_bounds__(256) void attn_kernel(
    const _Float16* __restrict__ q, const _Float16* __restrict__ k,
    const _Float16* __restrict__ v, const float* __restrict__ bias_table,
    const int* __restrict__ cidx, const int* __restrict__ p,
    _Float16* __restrict__ obuf)
{
    const int pp = threadIdx.x >> 7;
    const int tid = threadIdx.x & 127;
    const int blk = blockIdx.x * 2 + pp;
    const int b = blk / NHEAD, nh = blk % NHEAD;

    __shared__ int cI[2][TSEL], pI[2][TSEL];
    __shared__ float qal[2][TSEL][33];
    __shared__ float kh[2][NTOK][33];
    __shared__ float attnS[2][NTOK][33];
    __shared__ float gateS[2][NTOK];
    __shared__ float vs[2][TSEL][65];

    if (tid < TSEL) {
        cI[pp][tid] = cidx[blk * HD2 + tid];
        pI[pp][tid] = p[blk * TSEL + tid];
    }
    __syncthreads();

    // qal: 32x32 scalar gather (data-dependent indices)
    for (int idx = tid; idx < TSEL * HD2; idx += 128) {
        const int t = idx >> 5, j = idx & 31;
        qal[pp][t][j] = (float)q[((size_t)(b * NTOK + pI[pp][t])) * CDIM + nh * HDIM + cI[pp][j]] * SCALE_Q;
    }
    // kh: 49 rows x 4 f16x8 segments (vectorized)
    for (int idx = tid; idx < NTOK * 4; idx += 128) {
        const int i = idx >> 2, seg = idx & 3;
        const f16x8 kv = *reinterpret_cast<const f16x8*>(
            &k[((size_t)(b * NTOK + i)) * C2DIM + nh * HD2 + seg * 8]);
        #pragma unroll
        for (int u = 0; u < 8; ++u) kh[pp][i][seg * 8 + u] = (float)kv[u];
    }
    // vs: 32 rows x 8 f16x8 segments
    for (int idx = tid; idx < TSEL * 8; idx += 128) {
        const int t = idx >> 3, seg = idx & 7;
        const f16x8 vv = *reinterpret_cast<const f16x8*>(
            &v[((size_t)(b * TSEL + t)) * CDIM + nh * HDIM + seg * 8]);
        #pragma unroll
        for (int u = 0; u < 8; ++u) vs[pp][t][seg * 8 + u] = (float)vv[u];
    }
    __syncthreads();

    // QK^T + rel-pos bias
    {
        const int t = tid & 31;
        const int pt = pI[pp][t];
        const int pti = pt / 7, ptj = pt % 7;
        for (int i = tid >> 5; i < NTOK; i += 4) {
            const int ri = i / 7 - pti + 6;
            const int rj = i % 7 - ptj + 6;
            float a = bias_table[(ri * 13 + rj) * NHEAD + nh];
            #pragma unroll
            for (int j = 0; j < HD2; j++) a += kh[pp][i][j] * qal[pp][t][j];
            attnS[pp][i][t] = a;
        }
    }
    __syncthreads();

    // group-parallel softmax + gate: 4 lanes per row, 8 elements each
    {
        const int sub = tid & 3;
        for (int row = tid >> 2; row < NTOK; row += 32) {
            float x[8];
            float m = -INFINITY, tot = 0.f;
            #pragma unroll
            for (int u = 0; u < 8; ++u) {
                x[u] = attnS[pp][row][sub * 8 + u];
                m = fmaxf(m, x[u]);
                tot += x[u];
            }
            m = fmaxf(m, __shfl_xor(m, 1));
            m = fmaxf(m, __shfl_xor(m, 2));
            tot += __shfl_xor(tot, 1);
            tot += __shfl_xor(tot, 2);
            float s = 0.f;
            #pragma unroll
            for (int u = 0; u < 8; ++u) { x[u] = expf(x[u] - m); s += x[u]; }
            s += __shfl_xor(s, 1);
            s += __shfl_xor(s, 2);
            const float inv = 1.0f / s;
            #pragma unroll
            for (int u = 0; u < 8; ++u) attnS[pp][row][sub * 8 + u] = x[u] * inv;
            if (sub == 0)
                gateS[pp][row] = 1.0f / (1.0f + expf(-tot * (1.0f / 32.0f)));
        }
    }
    __syncthreads();

    // PV: thread owns 2 adjacent d columns; quarter-strided rows
    {
        const int d2 = (tid & 31) * 2;
        for (int i = tid >> 5; i < NTOK; i += 4) {
            float a0 = 0.f, a1 = 0.f;
            #pragma unroll
            for (int tt = 0; tt < TSEL; tt++) {
                const float w = attnS[pp][i][tt];
                a0 += w * vs[pp][tt][d2];
                a1 += w * vs[pp][tt][d2 + 1];
            }
            const float gg = gateS[pp][i];
            f16x2 o2 = {(_Float16)(a0 * gg), (_Float16)(a1 * gg)};
            *reinterpret_cast<f16x2*>(
                &obuf[((size_t)(b * NTOK + i)) * CDIM + nh * HDIM + d2]) = o2;
        }
    }
}

// ---------------------------------------------------------------------------
extern "C" void kernel_launch(void* const* d_in, const int* in_sizes, int n_in,
                              void* d_out, int out_size, void* d_ws, size_t ws_size,
                              hipStream_t stream)
{
    const float* x = (const float*)d_in[0];
    const float* Wq = (const float*)d_in[1];
    const float* bq = (const float*)d_in[2];
    const float* Wk = (const float*)d_in[3];
    const float* bk = (const float*)d_in[4];
    const float* Wv = (const float*)d_in[5];
    const float* bv = (const float*)d_in[6];
    const float* Wp = (const float*)d_in[7];
    const float* bp = (const float*)d_in[8];
    const float* Wc = (const float*)d_in[9];
    const float* bc = (const float*)d_in[10];
    const float* bias_table = (const float*)d_in[11];
    float* out = (float*)d_out;

    const size_t NQ = (size_t)MROWS * CDIM;
    char* wsp = (char*)d_ws;
    auto alloc = [&](size_t bytes) -> void* {
        void* pp = (void*)wsp;
        wsp += (bytes + 255) & ~(size_t)255;
        return pp;
    };

    _Float16* qbuf = (_Float16*)alloc(NQ * 2);                     // 154 MB
    _Float16* kbf = (_Float16*)alloc((size_t)MROWS * C2DIM * 2);   // 77 MB
    _Float16* vbf = (_Float16*)alloc((size_t)MVROWS * CDIM * 2);   // 100 MB
    _Float16* obf = (_Float16*)alloc(NQ * 2);                      // 154 MB
    float* rowmean = (float*)alloc((size_t)MROWS * NHEAD * 4);     // 4.8 MB
    float* psumA = (float*)alloc((size_t)BATCH * 2 * NHEAD * 64 * 4);
    float* pmaxA = (float*)alloc((size_t)BATCH * 2 * NHEAD * 64 * 4);
    int* cidx = (int*)alloc((size_t)BATCH * NHEAD * HD2 * 4);
    int* pidx = (int*)alloc((size_t)BATCH * NHEAD * TSEL * 4);
    if ((size_t)(wsp - (char*)d_ws) > ws_size) return;

    // 1) q = x @ Wq^T + bq (fp16x3 reg-staged, fused stats, fp16 qbuf)
    gemm_q_kernel<<<4704, 256, 0, stream>>>(
        x, Wq, bq, qbuf, rowmean, psumA, pmaxA);

    // 2) selections
    topk_kernel<<<BATCH * NHEAD, 64, 0, stream>>>(
        psumA, pmaxA, rowmean, bq, Wc, bc, cidx, pidx);

    // 3) k = gather_ch(q) @ Wk^T + bk  (fp16, BK=64, W rounded in-register)
    gemm_f16_kernel<1><<<2352, 256, 0, stream>>>(
        qbuf, Wk, bk, kbf, C2DIM, C2DIM, 294, 3, cidx);

    // 4) v = gather_tok(q) @ Wv^T + bv (fp16, BK=64)
    gemm_f16_kernel<2><<<3072, 256, 0, stream>>>(
        qbuf, Wv, bv, vbf, CDIM, CDIM, 384, 6, pidx);

    // 5) attention -> o fp16 (2 pairs per 256-thread block)
    attn_kernel<<<BATCH * NHEAD / 2, 256, 0, stream>>>(
        qbuf, kbf, vbf, bias_table, cidx, pidx, obf);

    // 6) out = o @ Wp^T + bp (fp16 -> fp32, BK=64)
    gemm_f16_kernel<0><<<4704, 256, 0, stream>>>(
        obf, Wp, bp, out, CDIM, CDIM, 588, 6, nullptr);
}

// Round 14
// 1362.221 us; speedup vs baseline: 1.0700x; 1.0700x over previous
//
#include <hip/hip_runtime.h>
#include <cmath>

#define NHEAD 12
#define NTOK 49
#define CDIM 768
#define C2DIM 384
#define HDIM 64
#define HD2 32
#define TSEL 32
#define BATCH 2048
#define MROWS (BATCH * NTOK)   // 100352
#define MVROWS (BATCH * TSEL)  // 65536
constexpr float SCALE_Q = 0.125f; // 64^-0.5

typedef _Float16 f16x8 __attribute__((ext_vector_type(8)));
typedef _Float16 f16x4 __attribute__((ext_vector_type(4)));
typedef _Float16 f16x2 __attribute__((ext_vector_type(2)));
typedef float f32x4 __attribute__((ext_vector_type(4)));

// fp16 2-limb split: x == hi + lo + O(2^-24 x)
__device__ __forceinline__ void split8(const float* v, f16x8& hi, f16x8& lo) {
    #pragma unroll
    for (int u = 0; u < 8; ++u) {
        const _Float16 h = (_Float16)v[u];
        hi[u] = h;
        lo[u] = (_Float16)(v[u] - (float)h);
    }
}
// XOR-swizzled granule index (involution; conflict-free proven R5-R13)
#define GIX(g) ((g) ^ ((((g) >> 7) & 3) << 1))

// ---------------------------------------------------------------------------
// fp32 -> fp16 weight convert (R12 proven — restored)
// ---------------------------------------------------------------------------
__global__ __launch_bounds__(256) void wconv_kernel(
    const float* __restrict__ src, _Float16* __restrict__ dst, int n4)
{
    const int stride = gridDim.x * blockDim.x;
    for (int i = blockIdx.x * blockDim.x + threadIdx.x; i < n4; i += stride) {
        const float4 v = reinterpret_cast<const float4*>(src)[i];
        f16x4 h = {(_Float16)v.x, (_Float16)v.y, (_Float16)v.z, (_Float16)v.w};
        reinterpret_cast<f16x4*>(dst)[i] = h;
    }
}

// ---------------------------------------------------------------------------
// q GEMM: R10-R12 loop + T14 async-STAGE split — global loads for tile k+1
// issued between the barriers (in flight across the MFMA phase).  Values and
// accumulation order bit-identical to R12.  __launch_bounds__(256,2).
// ---------------------------------------------------------------------------
__global__ __launch_bounds__(256, 2) void gemm_q_kernel(
    const float* __restrict__ A, const float* __restrict__ W,
    const float* __restrict__ bias, _Float16* __restrict__ Cq,
    float* __restrict__ rowmean, float* __restrict__ psumA,
    float* __restrict__ pmaxA)
{
    const int K = CDIM;
    __shared__ f16x8 AhiS[512], AloS[512], BhiS[512], BloS[512]; // 32 KB
    const int tid = threadIdx.x;
    const int lane = tid & 63, wid = tid >> 6;
    const int wr = wid >> 1, wc = wid & 1;
    const int g4 = lane >> 4, l15 = lane & 15;
    const int rsub = tid >> 2, kc = tid & 3;
    const int bid = blockIdx.x;                 // 4704 = 8 * 588
    const int vv = (bid & 7) * 588 + (bid >> 3);
    const int bx = vv / 6, by = vv % 6;
    const int mBase = bx * 128, nBase = by * 128;

    f32x4 acc[4][4] = {};
    float avA[2][8], avW[2][8]; // staging registers (issue-early)

    auto gload = [&](int kt) {
        #pragma unroll
        for (int pass = 0; pass < 2; ++pass) {
            const int row = rsub + pass * 64;
            const float* ap = &A[(size_t)(mBase + row) * K + kt + kc * 8];
            *reinterpret_cast<float4*>(&avA[pass][0]) = *reinterpret_cast<const float4*>(ap);
            *reinterpret_cast<float4*>(&avA[pass][4]) = *reinterpret_cast<const float4*>(ap + 4);
            const float* wp = &W[(size_t)(nBase + row) * K + kt + kc * 8];
            *reinterpret_cast<float4*>(&avW[pass][0]) = *reinterpret_cast<const float4*>(wp);
            *reinterpret_cast<float4*>(&avW[pass][4]) = *reinterpret_cast<const float4*>(wp + 4);
        }
    };

    gload(0);
    for (int kt = 0; kt < K; kt += 32) {
        __syncthreads(); // previous tile's reads done -> LDS reusable
        #pragma unroll
        for (int pass = 0; pass < 2; ++pass) {
            const int row = rsub + pass * 64;
            const int gi = GIX(kc * 128 + row);
            f16x8 h, l;
            split8(avA[pass], h, l);
            AhiS[gi] = h; AloS[gi] = l;
            split8(avW[pass], h, l);
            BhiS[gi] = h; BloS[gi] = l;
        }
        if (kt + 32 < K) gload(kt + 32); // next-tile loads fly during MFMA
        __syncthreads(); // tile ready

        const int ksl = g4 << 7;
        f16x8 ah[4], al[4], bh[4], bl[4];
        #pragma unroll
        for (int f = 0; f < 4; ++f) {
            ah[f] = AhiS[GIX(ksl + wr * 64 + f * 16 + l15)];
            al[f] = AloS[GIX(ksl + wr * 64 + f * 16 + l15)];
            bh[f] = BhiS[GIX(ksl + wc * 64 + f * 16 + l15)];
            bl[f] = BloS[GIX(ksl + wc * 64 + f * 16 + l15)];
        }
        #pragma unroll
        for (int i = 0; i < 4; ++i)
            #pragma unroll
            for (int j = 0; j < 4; ++j) {
                acc[i][j] = __builtin_amdgcn_mfma_f32_16x16x32_f16(ah[i], bh[j], acc[i][j], 0, 0, 0);
                acc[i][j] = __builtin_amdgcn_mfma_f32_16x16x32_f16(ah[i], bl[j], acc[i][j], 0, 0, 0);
                acc[i][j] = __builtin_amdgcn_mfma_f32_16x16x32_f16(al[i], bh[j], acc[i][j], 0, 0, 0);
            }
    }

    const int head = by * 2 + wc;

    // ---- C write (fp16, + bias)
    #pragma unroll
    for (int i = 0; i < 4; ++i) {
        #pragma unroll
        for (int j = 0; j < 4; ++j) {
            const int col = nBase + wc * 64 + j * 16 + l15;
            const float bv = bias[col];
            #pragma unroll
            for (int r = 0; r < 4; ++r) {
                const int rowg = mBase + wr * 64 + i * 16 + g4 * 4 + r;
                Cq[(size_t)rowg * CDIM + col] = (_Float16)(acc[i][j][r] + bv);
            }
        }
    }

    // ---- rowmean (exact, deterministic) over this wave's 64 head cols
    float bsum = 0.f;
    #pragma unroll
    for (int j = 0; j < 4; ++j) bsum += bias[nBase + wc * 64 + j * 16 + l15];
    #pragma unroll
    for (int off = 1; off < 16; off <<= 1) bsum += __shfl_xor(bsum, off);

    const int R0 = mBase + wr * 64;
    #pragma unroll
    for (int i = 0; i < 4; ++i) {
        #pragma unroll
        for (int r = 0; r < 4; ++r) {
            float s = acc[i][0][r] + acc[i][1][r] + acc[i][2][r] + acc[i][3][r];
            #pragma unroll
            for (int off = 1; off < 16; off <<= 1) s += __shfl_xor(s, off);
            if (l15 == 0)
                rowmean[(size_t)(R0 + i * 16 + g4 * 4 + r) * NHEAD + head] =
                    (s + bsum) * (1.0f / 64.0f);
        }
    }

    // ---- channel sum/max partials per 64-row window segment
    const int bS = R0 / NTOK, bE = (R0 + 63) / NTOK;
    for (int b = bS; b <= bE; ++b) {
        const int lo = (49 * b > R0 ? 49 * b - R0 : 0);
        const int hiB = 49 * b + 49;
        const int hi = (hiB < R0 + 64 ? hiB - R0 : 64);
        float ps[4] = {0.f, 0.f, 0.f, 0.f};
        float pm[4] = {-INFINITY, -INFINITY, -INFINITY, -INFINITY};
        #pragma unroll
        for (int i = 0; i < 4; ++i) {
            #pragma unroll
            for (int r = 0; r < 4; ++r) {
                const int rl_ = i * 16 + g4 * 4 + r;
                if (rl_ >= lo && rl_ < hi) {
                    #pragma unroll
                    for (int j = 0; j < 4; ++j) {
                        ps[j] += acc[i][j][r];
                        pm[j] = fmaxf(pm[j], acc[i][j][r]);
                    }
                }
            }
        }
        #pragma unroll
        for (int j = 0; j < 4; ++j) {
            ps[j] += __shfl_xor(ps[j], 16);
            ps[j] += __shfl_xor(ps[j], 32);
            pm[j] = fmaxf(pm[j], __shfl_xor(pm[j], 16));
            pm[j] = fmaxf(pm[j], __shfl_xor(pm[j], 32));
        }
        const int which = (R0 >> 6) - ((49 * b) >> 6); // 0 or 1
        if (lane < 16) {
            #pragma unroll
            for (int j = 0; j < 4; ++j) {
                const int idx = ((b * 2 + which) * NHEAD + head) * 64 + j * 16 + lane;
                psumA[idx] = ps[j];
                pmaxA[idx] = pm[j];
            }
        }
    }
}

// ---------------------------------------------------------------------------
// Combine partials + top-k selections. Rank selection == lax.top_k + sort.
// ---------------------------------------------------------------------------
__global__ __launch_bounds__(64) void topk_kernel(
    const float* __restrict__ psumA, const float* __restrict__ pmaxA,
    const float* __restrict__ rowmean, const float* __restrict__ bq,
    const float* __restrict__ Wc, const float* __restrict__ bc,
    int* __restrict__ cidx, int* __restrict__ p)
{
    const int blk = blockIdx.x;
    const int b = blk / NHEAD, nh = blk % NHEAD;
    const int tid = threadIdx.x;

    __shared__ float chmean[64], chmax[64], rs[NTOK], logits[64];

    {
        const int i0 = ((b * 2 + 0) * NHEAD + nh) * 64 + tid;
        float s = psumA[i0];
        float m = pmaxA[i0];
        if (((49 * b) >> 6) != ((49 * b + 48) >> 6)) {
            const int i1 = ((b * 2 + 1) * NHEAD + nh) * 64 + tid;
            s += psumA[i1];
            m = fmaxf(m, pmaxA[i1]);
        }
        const float bqv = bq[nh * 64 + tid];
        chmean[tid] = s * (1.0f / 49.0f) + bqv;
        chmax[tid] = m + bqv;
    }
    if (tid < NTOK) rs[tid] = rowmean[(size_t)(b * NTOK + tid) * NHEAD + nh];
    __syncthreads();

    float accv = bc[tid];
    const float* wrow = Wc + tid * 128;
    for (int c = 0; c < 64; c++) accv += chmean[c] * wrow[c];
    for (int c = 0; c < 64; c++) accv += chmax[c] * wrow[64 + c];
    const float gl = 0.5f * accv * (1.0f + erff(accv * 0.70710678118654752f));
    logits[tid] = gl;
    __syncthreads();

    int rank = 0;
    for (int kk = 0; kk < 64; kk++) {
        const float o = logits[kk];
        rank += (o > gl) || (o == gl && kk < tid);
    }
    const bool sel = rank < HD2;
    const unsigned long long mask = __ballot(sel);
    if (sel) {
        const int pos = __popcll(mask & ((1ull << tid) - 1ull));
        cidx[blk * HD2 + pos] = tid;
    }
    __syncthreads();

    if (tid < NTOK) {
        const float rv = rs[tid];
        int rank2 = 0;
        for (int m = 0; m < NTOK; m++) {
            const float o = rs[m];
            rank2 += (o > rv) || (o == rv && m < tid);
        }
        const bool sel2 = rank2 < TSEL;
        const unsigned long long mask2 = __ballot(sel2);
        if (sel2) {
            const int pos = __popcll(mask2 & ((1ull << tid) - 1ull));
            p[blk * TSEL + pos] = tid;
        }
    }
}

// ---------------------------------------------------------------------------
// Reg-staged plain-fp16 GEMM, BK=64 (R11/R12 proven — fp16 weights restored).
// MODE 0: A = fp16 row-major (o buffer), fp32 output
// MODE 1: A = channel-gather from fp16 q (cidx), fp16 output (k)
// MODE 2: A = token-gather rows from fp16 q (pidx), fp16 output (v)
// ---------------------------------------------------------------------------
template <int MODE>
__global__ __launch_bounds__(256, 2) void gemm_f16_kernel(
    const void* __restrict__ Asrc, const _Float16* __restrict__ Bw,
    const float* __restrict__ bias, void* __restrict__ Cout,
    int N, int K, int PER, int F, const int* __restrict__ gidx)
{
    __shared__ f16x8 AS[1024], BS[1024]; // 32 KB
    const int tid = threadIdx.x;
    const int lane = tid & 63, wid = tid >> 6;
    const int wr = wid >> 1, wc = wid & 1;
    const int bid = blockIdx.x;
    const int vv = (bid & 7) * PER + (bid >> 3);
    const int mBase = (vv / F) * 128, nBase = (vv % F) * 128;
    const int rsub = tid >> 2, kc = tid & 3;

    f32x4 acc[4][4] = {};

    for (int kt = 0; kt < K; kt += 64) {
        __syncthreads();
        #pragma unroll
        for (int pass = 0; pass < 2; ++pass) {
            const int row = rsub + pass * 64;
            #pragma unroll
            for (int half = 0; half < 2; ++half) {
                const int ks = kc + half * 4;
                const int g = ks * 128 + row;
                const int gi = GIX(g);
                const int kg = kt + ks * 8;
                if (MODE == 0) {
                    const _Float16* ap = (const _Float16*)Asrc;
                    AS[gi] = *reinterpret_cast<const f16x8*>(
                        &ap[(size_t)(mBase + row) * K + kg]);
                } else if (MODE == 1) {
                    const _Float16* Q = (const _Float16*)Asrc;
                    const int gm = mBase + row;
                    const int b = gm / NTOK;
                    const int nh = kg >> 5;
                    const int* cp = &gidx[(b * NHEAD + nh) * HD2 + (kg & 31)];
                    const int4 c0 = *reinterpret_cast<const int4*>(cp);
                    const int4 c1 = *reinterpret_cast<const int4*>(cp + 4);
                    const _Float16* qp = &Q[(size_t)gm * CDIM + nh * HDIM];
                    f16x8 h;
                    h[0] = qp[c0.x]; h[1] = qp[c0.y]; h[2] = qp[c0.z]; h[3] = qp[c0.w];
                    h[4] = qp[c1.x]; h[5] = qp[c1.y]; h[6] = qp[c1.z]; h[7] = qp[c1.w];
                    AS[gi] = h;
                } else { // MODE 2
                    const _Float16* Q = (const _Float16*)Asrc;
                    const int gm = mBase + row;
                    const int b = gm >> 5, t = gm & 31;
                    const int nh = kg >> 6;
                    const int row2 = gidx[(b * NHEAD + nh) * TSEL + t];
                    AS[gi] = *reinterpret_cast<const f16x8*>(
                        &Q[(size_t)(b * NTOK + row2) * CDIM + kg]);
                }
                BS[gi] = *reinterpret_cast<const f16x8*>(
                    &Bw[(size_t)(nBase + row) * K + kg]);
            }
        }
        __syncthreads();

        const int rl = lane & 15;
        #pragma unroll
        for (int half = 0; half < 2; ++half) {
            const int ksl = ((lane >> 4) + half * 4) << 7;
            f16x8 af[4], bf[4];
            #pragma unroll
            for (int f = 0; f < 4; ++f) {
                af[f] = AS[GIX(ksl + wr * 64 + f * 16 + rl)];
                bf[f] = BS[GIX(ksl + wc * 64 + f * 16 + rl)];
            }
            #pragma unroll
            for (int i = 0; i < 4; ++i)
                #pragma unroll
                for (int j = 0; j < 4; ++j)
                    acc[i][j] = __builtin_amdgcn_mfma_f32_16x16x32_f16(af[i], bf[j], acc[i][j], 0, 0, 0);
        }
    }

    #pragma unroll
    for (int i = 0; i < 4; ++i) {
        const int rbase = mBase + wr * 64 + i * 16 + ((lane >> 4) << 2);
        #pragma unroll
        for (int j = 0; j < 4; ++j) {
            const int col = nBase + wc * 64 + j * 16 + (lane & 15);
            const float bv = bias[col];
            #pragma unroll
            for (int r = 0; r < 4; ++r) {
                const float o = acc[i][j][r] + bv;
                if (MODE == 0)
                    ((float*)Cout)[(size_t)(rbase + r) * N + col] = o;
                else
                    ((_Float16*)Cout)[(size_t)(rbase + r) * N + col] = (_Float16)o;
            }
        }
    }
}

// ---------------------------------------------------------------------------
// Per (b, nh) attention; 128 threads (R12 proven — restored). q/k/v fp16 in,
// fp32 math, o fp16 out. Vectorized staging + 4-lane-group parallel softmax.
// ---------------------------------------------------------------------------
__global__ __launch_bounds__(128) void attn_kernel(
    const _Float16* __restrict__ q, const _Float16* __restrict__ k,
    const _Float16* __restrict__ v, const float* __restrict__ bias_table,
    const int* __restrict__ cidx, const int* __restrict__ p,
    _Float16* __restrict__ obuf)
{
    const int blk = blockIdx.x;
    const int b = blk / NHEAD, nh = blk % NHEAD;
    const int tid = threadIdx.x;

    __shared__ int cI[TSEL], pI[TSEL];
    __shared__ float qal[TSEL][33];
    __shared__ float kh[NTOK][33];
    __shared__ float attnS[NTOK][33];
    __shared__ float gateS[NTOK];
    __shared__ float vs[TSEL][65];

    if (tid < TSEL) {
        cI[tid] = cidx[blk * HD2 + tid];
        pI[tid] = p[blk * TSEL + tid];
    }
    __syncthreads();

    for (int idx = tid; idx < TSEL * HD2; idx += 128) {
        const int t = idx >> 5, j = idx & 31;
        qal[t][j] = (float)q[((size_t)(b * NTOK + pI[t])) * CDIM + nh * HDIM + cI[j]] * SCALE_Q;
    }
    for (int idx = tid; idx < NTOK * 4; idx += 128) {
        const int i = idx >> 2, seg = idx & 3;
        const f16x8 kv = *reinterpret_cast<const f16x8*>(
            &k[((size_t)(b * NTOK + i)) * C2DIM + nh * HD2 + seg * 8]);
        #pragma unroll
        for (int u = 0; u < 8; ++u) kh[i][seg * 8 + u] = (float)kv[u];
    }
    for (int idx = tid; idx < TSEL * 8; idx += 128) {
        const int t = idx >> 3, seg = idx & 7;
        const f16x8 vv = *reinterpret_cast<const f16x8*>(
            &v[((size_t)(b * TSEL + t)) * CDIM + nh * HDIM + seg * 8]);
        #pragma unroll
        for (int u = 0; u < 8; ++u) vs[t][seg * 8 + u] = (float)vv[u];
    }
    __syncthreads();

    {
        const int t = tid & 31;
        const int pt = pI[t];
        const int pti = pt / 7, ptj = pt % 7;
        for (int i = tid >> 5; i < NTOK; i += 4) {
            const int ri = i / 7 - pti + 6;
            const int rj = i % 7 - ptj + 6;
            float a = bias_table[(ri * 13 + rj) * NHEAD + nh];
            #pragma unroll
            for (int j = 0; j < HD2; j++) a += kh[i][j] * qal[t][j];
            attnS[i][t] = a;
        }
    }
    __syncthreads();

    {
        const int sub = tid & 3;
        for (int row = tid >> 2; row < NTOK; row += 32) {
            float x[8];
            float m = -INFINITY, tot = 0.f;
            #pragma unroll
            for (int u = 0; u < 8; ++u) {
                x[u] = attnS[row][sub * 8 + u];
                m = fmaxf(m, x[u]);
                tot += x[u];
            }
            m = fmaxf(m, __shfl_xor(m, 1));
            m = fmaxf(m, __shfl_xor(m, 2));
            tot += __shfl_xor(tot, 1);
            tot += __shfl_xor(tot, 2);
            float s = 0.f;
            #pragma unroll
            for (int u = 0; u < 8; ++u) { x[u] = expf(x[u] - m); s += x[u]; }
            s += __shfl_xor(s, 1);
            s += __shfl_xor(s, 2);
            const float inv = 1.0f / s;
            #pragma unroll
            for (int u = 0; u < 8; ++u) attnS[row][sub * 8 + u] = x[u] * inv;
            if (sub == 0)
                gateS[row] = 1.0f / (1.0f + expf(-tot * (1.0f / 32.0f)));
        }
    }
    __syncthreads();

    {
        const int d2 = (tid & 31) * 2;
        for (int i = tid >> 5; i < NTOK; i += 4) {
            float a0 = 0.f, a1 = 0.f;
            #pragma unroll
            for (int tt = 0; tt < TSEL; tt++) {
                const float w = attnS[i][tt];
                a0 += w * vs[tt][d2];
                a1 += w * vs[tt][d2 + 1];
            }
            const float gg = gateS[i];
            f16x2 o2 = {(_Float16)(a0 * gg), (_Float16)(a1 * gg)};
            *reinterpret_cast<f16x2*>(
                &obuf[((size_t)(b * NTOK + i)) * CDIM + nh * HDIM + d2]) = o2;
        }
    }
}

// ---------------------------------------------------------------------------
extern "C" void kernel_launch(void* const* d_in, const int* in_sizes, int n_in,
                              void* d_out, int out_size, void* d_ws, size_t ws_size,
                              hipStream_t stream)
{
    const float* x = (const float*)d_in[0];
    const float* Wq = (const float*)d_in[1];
    const float* bq = (const float*)d_in[2];
    const float* Wk = (const float*)d_in[3];
    const float* bk = (const float*)d_in[4];
    const float* Wv = (const float*)d_in[5];
    const float* bv = (const float*)d_in[6];
    const float* Wp = (const float*)d_in[7];
    const float* bp = (const float*)d_in[8];
    const float* Wc = (const float*)d_in[9];
    const float* bc = (const float*)d_in[10];
    const float* bias_table = (const float*)d_in[11];
    float* out = (float*)d_out;

    const size_t NQ = (size_t)MROWS * CDIM;
    char* wsp = (char*)d_ws;
    auto alloc = [&](size_t bytes) -> void* {
        void* pp = (void*)wsp;
        wsp += (bytes + 255) & ~(size_t)255;
        return pp;
    };

    _Float16* qbuf = (_Float16*)alloc(NQ * 2);                     // 154 MB
    _Float16* kbf = (_Float16*)alloc((size_t)MROWS * C2DIM * 2);   // 77 MB
    _Float16* vbf = (_Float16*)alloc((size_t)MVROWS * CDIM * 2);   // 100 MB
    _Float16* obf = (_Float16*)alloc(NQ * 2);                      // 154 MB
    float* rowmean = (float*)alloc((size_t)MROWS * NHEAD * 4);     // 4.8 MB
    float* psumA = (float*)alloc((size_t)BATCH * 2 * NHEAD * 64 * 4);
    float* pmaxA = (float*)alloc((size_t)BATCH * 2 * NHEAD * 64 * 4);
    _Float16* wk16 = (_Float16*)alloc((size_t)C2DIM * C2DIM * 2);
    _Float16* wv16 = (_Float16*)alloc((size_t)CDIM * CDIM * 2);
    _Float16* wp16 = (_Float16*)alloc((size_t)CDIM * CDIM * 2);
    int* cidx = (int*)alloc((size_t)BATCH * NHEAD * HD2 * 4);
    int* pidx = (int*)alloc((size_t)BATCH * NHEAD * TSEL * 4);
    if ((size_t)(wsp - (char*)d_ws) > ws_size) return;

    // 0) pre-convert post-decision weights to fp16 (R12 proven)
    wconv_kernel<<<144, 256, 0, stream>>>(Wk, wk16, C2DIM * C2DIM / 4);
    wconv_kernel<<<256, 256, 0, stream>>>(Wv, wv16, CDIM * CDIM / 4);
    wconv_kernel<<<256, 256, 0, stream>>>(Wp, wp16, CDIM * CDIM / 4);

    // 1) q = x @ Wq^T + bq (fp16x3 reg-staged + T14 async-stage, fused stats)
    gemm_q_kernel<<<4704, 256, 0, stream>>>(
        x, Wq, bq, qbuf, rowmean, psumA, pmaxA);

    // 2) selections
    topk_kernel<<<BATCH * NHEAD, 64, 0, stream>>>(
        psumA, pmaxA, rowmean, bq, Wc, bc, cidx, pidx);

    // 3) k = gather_ch(q) @ Wk^T + bk  (fp16, BK=64)
    gemm_f16_kernel<1><<<2352, 256, 0, stream>>>(
        qbuf, wk16, bk, kbf, C2DIM, C2DIM, 294, 3, cidx);

    // 4) v = gather_tok(q) @ Wv^T + bv (fp16, BK=64)
    gemm_f16_kernel<2><<<3072, 256, 0, stream>>>(
        qbuf, wv16, bv, vbf, CDIM, CDIM, 384, 6, pidx);

    // 5) attention -> o fp16 (128 threads, 1 pair — R12 proven)
    attn_kernel<<<BATCH * NHEAD, 128, 0, stream>>>(
        qbuf, kbf, vbf, bias_table, cidx, pidx, obf);

    // 6) out = o @ Wp^T + bp (fp16 -> fp32, BK=64)
    gemm_f16_kernel<0><<<4704, 256, 0, stream>>>(
        obf, wp16, bp, out, CDIM, CDIM, 588, 6, nullptr);
}

// Round 15
// 1332.508 us; speedup vs baseline: 1.0939x; 1.0223x over previous
//
#include <hip/hip_runtime.h>
#include <cmath>

#define NHEAD 12
#define NTOK 49
#define CDIM 768
#define C2DIM 384
#define HDIM 64
#define HD2 32
#define TSEL 32
#define BATCH 2048
#define MROWS (BATCH * NTOK)   // 100352
#define MVROWS (BATCH * TSEL)  // 65536
constexpr float SCALE_Q = 0.125f; // 64^-0.5

typedef _Float16 f16x8 __attribute__((ext_vector_type(8)));
typedef _Float16 f16x4 __attribute__((ext_vector_type(4)));
typedef _Float16 f16x2 __attribute__((ext_vector_type(2)));
typedef float f32x4 __attribute__((ext_vector_type(4)));

// fp16 2-limb split: x == hi + lo + O(2^-24 x)
__device__ __forceinline__ void split8(const float* v, f16x8& hi, f16x8& lo) {
    #pragma unroll
    for (int u = 0; u < 8; ++u) {
        const _Float16 h = (_Float16)v[u];
        hi[u] = h;
        lo[u] = (_Float16)(v[u] - (float)h);
    }
}
// XOR-swizzled granule index (involution; conflict-free proven R5-R14)
#define GIX(g) ((g) ^ ((((g) >> 7) & 3) << 1))

// ---------------------------------------------------------------------------
// fp32 -> fp16 weight convert
// ---------------------------------------------------------------------------
__global__ __launch_bounds__(256) void wconv_kernel(
    const float* __restrict__ src, _Float16* __restrict__ dst, int n4)
{
    const int stride = gridDim.x * blockDim.x;
    for (int i = blockIdx.x * blockDim.x + threadIdx.x; i < n4; i += stride) {
        const float4 v = reinterpret_cast<const float4*>(src)[i];
        f16x4 h = {(_Float16)v.x, (_Float16)v.y, (_Float16)v.z, (_Float16)v.w};
        reinterpret_cast<f16x4*>(dst)[i] = h;
    }
}

// ---------------------------------------------------------------------------
// q GEMM (R10-R12 proven, 430 us): reg-staged 128x128 / 4-wave / BK=32
// fp16x3 split loop + fused-stats epilogue.  __launch_bounds__(256,2).
// ---------------------------------------------------------------------------
__global__ __launch_bounds__(256, 2) void gemm_q_kernel(
    const float* __restrict__ A, const float* __restrict__ W,
    const float* __restrict__ bias, _Float16* __restrict__ Cq,
    float* __restrict__ rowmean, float* __restrict__ psumA,
    float* __restrict__ pmaxA)
{
    const int K = CDIM;
    __shared__ f16x8 AhiS[512], AloS[512], BhiS[512], BloS[512]; // 32 KB
    const int tid = threadIdx.x;
    const int lane = tid & 63, wid = tid >> 6;
    const int wr = wid >> 1, wc = wid & 1;
    const int g4 = lane >> 4, l15 = lane & 15;
    const int rsub = tid >> 2, kc = tid & 3;
    const int bid = blockIdx.x;                 // 4704 = 8 * 588
    const int vv = (bid & 7) * 588 + (bid >> 3);
    const int bx = vv / 6, by = vv % 6;
    const int mBase = bx * 128, nBase = by * 128;

    f32x4 acc[4][4] = {};

    for (int kt = 0; kt < K; kt += 32) {
        __syncthreads();
        #pragma unroll
        for (int pass = 0; pass < 2; ++pass) {
            const int row = rsub + pass * 64;
            const int g = kc * 128 + row;
            const int gi = GIX(g);
            {
                const float* ap = &A[(size_t)(mBase + row) * K + kt + kc * 8];
                float av[8];
                *reinterpret_cast<float4*>(&av[0]) = *reinterpret_cast<const float4*>(ap);
                *reinterpret_cast<float4*>(&av[4]) = *reinterpret_cast<const float4*>(ap + 4);
                f16x8 h, l; split8(av, h, l);
                AhiS[gi] = h; AloS[gi] = l;
            }
            {
                const float* wp = &W[(size_t)(nBase + row) * K + kt + kc * 8];
                float wv[8];
                *reinterpret_cast<float4*>(&wv[0]) = *reinterpret_cast<const float4*>(wp);
                *reinterpret_cast<float4*>(&wv[4]) = *reinterpret_cast<const float4*>(wp + 4);
                f16x8 h, l; split8(wv, h, l);
                BhiS[gi] = h; BloS[gi] = l;
            }
        }
        __syncthreads();

        const int ksl = g4 << 7;
        f16x8 ah[4], al[4], bh[4], bl[4];
        #pragma unroll
        for (int f = 0; f < 4; ++f) {
            ah[f] = AhiS[GIX(ksl + wr * 64 + f * 16 + l15)];
            al[f] = AloS[GIX(ksl + wr * 64 + f * 16 + l15)];
            bh[f] = BhiS[GIX(ksl + wc * 64 + f * 16 + l15)];
            bl[f] = BloS[GIX(ksl + wc * 64 + f * 16 + l15)];
        }
        #pragma unroll
        for (int i = 0; i < 4; ++i)
            #pragma unroll
            for (int j = 0; j < 4; ++j) {
                acc[i][j] = __builtin_amdgcn_mfma_f32_16x16x32_f16(ah[i], bh[j], acc[i][j], 0, 0, 0);
                acc[i][j] = __builtin_amdgcn_mfma_f32_16x16x32_f16(ah[i], bl[j], acc[i][j], 0, 0, 0);
                acc[i][j] = __builtin_amdgcn_mfma_f32_16x16x32_f16(al[i], bh[j], acc[i][j], 0, 0, 0);
            }
    }

    const int head = by * 2 + wc;

    // ---- C write (fp16, + bias)
    #pragma unroll
    for (int i = 0; i < 4; ++i) {
        #pragma unroll
        for (int j = 0; j < 4; ++j) {
            const int col = nBase + wc * 64 + j * 16 + l15;
            const float bv = bias[col];
            #pragma unroll
            for (int r = 0; r < 4; ++r) {
                const int rowg = mBase + wr * 64 + i * 16 + g4 * 4 + r;
                Cq[(size_t)rowg * CDIM + col] = (_Float16)(acc[i][j][r] + bv);
            }
        }
    }

    // ---- rowmean (exact, deterministic) over this wave's 64 head cols
    float bsum = 0.f;
    #pragma unroll
    for (int j = 0; j < 4; ++j) bsum += bias[nBase + wc * 64 + j * 16 + l15];
    #pragma unroll
    for (int off = 1; off < 16; off <<= 1) bsum += __shfl_xor(bsum, off);

    const int R0 = mBase + wr * 64;
    #pragma unroll
    for (int i = 0; i < 4; ++i) {
        #pragma unroll
        for (int r = 0; r < 4; ++r) {
            float s = acc[i][0][r] + acc[i][1][r] + acc[i][2][r] + acc[i][3][r];
            #pragma unroll
            for (int off = 1; off < 16; off <<= 1) s += __shfl_xor(s, off);
            if (l15 == 0)
                rowmean[(size_t)(R0 + i * 16 + g4 * 4 + r) * NHEAD + head] =
                    (s + bsum) * (1.0f / 64.0f);
        }
    }

    // ---- channel sum/max partials per 64-row window segment
    const int bS = R0 / NTOK, bE = (R0 + 63) / NTOK;
    for (int b = bS; b <= bE; ++b) {
        const int lo = (49 * b > R0 ? 49 * b - R0 : 0);
        const int hiB = 49 * b + 49;
        const int hi = (hiB < R0 + 64 ? hiB - R0 : 64);
        float ps[4] = {0.f, 0.f, 0.f, 0.f};
        float pm[4] = {-INFINITY, -INFINITY, -INFINITY, -INFINITY};
        #pragma unroll
        for (int i = 0; i < 4; ++i) {
            #pragma unroll
            for (int r = 0; r < 4; ++r) {
                const int rl_ = i * 16 + g4 * 4 + r;
                if (rl_ >= lo && rl_ < hi) {
                    #pragma unroll
                    for (int j = 0; j < 4; ++j) {
                        ps[j] += acc[i][j][r];
                        pm[j] = fmaxf(pm[j], acc[i][j][r]);
                    }
                }
            }
        }
        #pragma unroll
        for (int j = 0; j < 4; ++j) {
            ps[j] += __shfl_xor(ps[j], 16);
            ps[j] += __shfl_xor(ps[j], 32);
            pm[j] = fmaxf(pm[j], __shfl_xor(pm[j], 16));
            pm[j] = fmaxf(pm[j], __shfl_xor(pm[j], 32));
        }
        const int which = (R0 >> 6) - ((49 * b) >> 6); // 0 or 1
        if (lane < 16) {
            #pragma unroll
            for (int j = 0; j < 4; ++j) {
                const int idx = ((b * 2 + which) * NHEAD + head) * 64 + j * 16 + lane;
                psumA[idx] = ps[j];
                pmaxA[idx] = pm[j];
            }
        }
    }
}

// ---------------------------------------------------------------------------
// Combine partials + top-k selections. Rank selection == lax.top_k + sort.
// ---------------------------------------------------------------------------
__global__ __launch_bounds__(64) void topk_kernel(
    const float* __restrict__ psumA, const float* __restrict__ pmaxA,
    const float* __restrict__ rowmean, const float* __restrict__ bq,
    const float* __restrict__ Wc, const float* __restrict__ bc,
    int* __restrict__ cidx, int* __restrict__ p)
{
    const int blk = blockIdx.x;
    const int b = blk / NHEAD, nh = blk % NHEAD;
    const int tid = threadIdx.x;

    __shared__ float chmean[64], chmax[64], rs[NTOK], logits[64];

    {
        const int i0 = ((b * 2 + 0) * NHEAD + nh) * 64 + tid;
        float s = psumA[i0];
        float m = pmaxA[i0];
        if (((49 * b) >> 6) != ((49 * b + 48) >> 6)) {
            const int i1 = ((b * 2 + 1) * NHEAD + nh) * 64 + tid;
            s += psumA[i1];
            m = fmaxf(m, pmaxA[i1]);
        }
        const float bqv = bq[nh * 64 + tid];
        chmean[tid] = s * (1.0f / 49.0f) + bqv;
        chmax[tid] = m + bqv;
    }
    if (tid < NTOK) rs[tid] = rowmean[(size_t)(b * NTOK + tid) * NHEAD + nh];
    __syncthreads();

    float accv = bc[tid];
    const float* wrow = Wc + tid * 128;
    for (int c = 0; c < 64; c++) accv += chmean[c] * wrow[c];
    for (int c = 0; c < 64; c++) accv += chmax[c] * wrow[64 + c];
    const float gl = 0.5f * accv * (1.0f + erff(accv * 0.70710678118654752f));
    logits[tid] = gl;
    __syncthreads();

    int rank = 0;
    for (int kk = 0; kk < 64; kk++) {
        const float o = logits[kk];
        rank += (o > gl) || (o == gl && kk < tid);
    }
    const bool sel = rank < HD2;
    const unsigned long long mask = __ballot(sel);
    if (sel) {
        const int pos = __popcll(mask & ((1ull << tid) - 1ull));
        cidx[blk * HD2 + pos] = tid;
    }
    __syncthreads();

    if (tid < NTOK) {
        const float rv = rs[tid];
        int rank2 = 0;
        for (int m = 0; m < NTOK; m++) {
            const float o = rs[m];
            rank2 += (o > rv) || (o == rv && m < tid);
        }
        const bool sel2 = rank2 < TSEL;
        const unsigned long long mask2 = __ballot(sel2);
        if (sel2) {
            const int pos = __popcll(mask2 & ((1ull << tid) - 1ull));
            p[blk * TSEL + pos] = tid;
        }
    }
}

// ---------------------------------------------------------------------------
// Reg-staged plain-fp16 GEMM, BK=64 (R11/R12 proven).
// MODE 0: A = fp16 row-major (o buffer), fp32 output
// MODE 1: A = channel-gather from fp16 q (cidx), fp16 output (k)
// MODE 2: A = token-gather rows from fp16 q (pidx), fp16 output (v)
// ---------------------------------------------------------------------------
template <int MODE>
__global__ __launch_bounds__(256, 2) void gemm_f16_kernel(
    const void* __restrict__ Asrc, const _Float16* __restrict__ Bw,
    const float* __restrict__ bias, void* __restrict__ Cout,
    int N, int K, int PER, int F, const int* __restrict__ gidx)
{
    __shared__ f16x8 AS[1024], BS[1024]; // 32 KB
    const int tid = threadIdx.x;
    const int lane = tid & 63, wid = tid >> 6;
    const int wr = wid >> 1, wc = wid & 1;
    const int bid = blockIdx.x;
    const int vv = (bid & 7) * PER + (bid >> 3);
    const int mBase = (vv / F) * 128, nBase = (vv % F) * 128;
    const int rsub = tid >> 2, kc = tid & 3;

    f32x4 acc[4][4] = {};

    for (int kt = 0; kt < K; kt += 64) {
        __syncthreads();
        #pragma unroll
        for (int pass = 0; pass < 2; ++pass) {
            const int row = rsub + pass * 64;
            #pragma unroll
            for (int half = 0; half < 2; ++half) {
                const int ks = kc + half * 4;
                const int g = ks * 128 + row;
                const int gi = GIX(g);
                const int kg = kt + ks * 8;
                if (MODE == 0) {
                    const _Float16* ap = (const _Float16*)Asrc;
                    AS[gi] = *reinterpret_cast<const f16x8*>(
                        &ap[(size_t)(mBase + row) * K + kg]);
                } else if (MODE == 1) {
                    const _Float16* Q = (const _Float16*)Asrc;
                    const int gm = mBase + row;
                    const int b = gm / NTOK;
                    const int nh = kg >> 5;
                    const int* cp = &gidx[(b * NHEAD + nh) * HD2 + (kg & 31)];
                    const int4 c0 = *reinterpret_cast<const int4*>(cp);
                    const int4 c1 = *reinterpret_cast<const int4*>(cp + 4);
                    const _Float16* qp = &Q[(size_t)gm * CDIM + nh * HDIM];
                    f16x8 h;
                    h[0] = qp[c0.x]; h[1] = qp[c0.y]; h[2] = qp[c0.z]; h[3] = qp[c0.w];
                    h[4] = qp[c1.x]; h[5] = qp[c1.y]; h[6] = qp[c1.z]; h[7] = qp[c1.w];
                    AS[gi] = h;
                } else { // MODE 2
                    const _Float16* Q = (const _Float16*)Asrc;
                    const int gm = mBase + row;
                    const int b = gm >> 5, t = gm & 31;
                    const int nh = kg >> 6;
                    const int row2 = gidx[(b * NHEAD + nh) * TSEL + t];
                    AS[gi] = *reinterpret_cast<const f16x8*>(
                        &Q[(size_t)(b * NTOK + row2) * CDIM + kg]);
                }
                BS[gi] = *reinterpret_cast<const f16x8*>(
                    &Bw[(size_t)(nBase + row) * K + kg]);
            }
        }
        __syncthreads();

        const int rl = lane & 15;
        #pragma unroll
        for (int half = 0; half < 2; ++half) {
            const int ksl = ((lane >> 4) + half * 4) << 7;
            f16x8 af[4], bf[4];
            #pragma unroll
            for (int f = 0; f < 4; ++f) {
                af[f] = AS[GIX(ksl + wr * 64 + f * 16 + rl)];
                bf[f] = BS[GIX(ksl + wc * 64 + f * 16 + rl)];
            }
            #pragma unroll
            for (int i = 0; i < 4; ++i)
                #pragma unroll
                for (int j = 0; j < 4; ++j)
                    acc[i][j] = __builtin_amdgcn_mfma_f32_16x16x32_f16(af[i], bf[j], acc[i][j], 0, 0, 0);
        }
    }

    #pragma unroll
    for (int i = 0; i < 4; ++i) {
        const int rbase = mBase + wr * 64 + i * 16 + ((lane >> 4) << 2);
        #pragma unroll
        for (int j = 0; j < 4; ++j) {
            const int col = nBase + wc * 64 + j * 16 + (lane & 15);
            const float bv = bias[col];
            #pragma unroll
            for (int r = 0; r < 4; ++r) {
                const float o = acc[i][j][r] + bv;
                if (MODE == 0)
                    ((float*)Cout)[(size_t)(rbase + r) * N + col] = o;
                else
                    ((_Float16*)Cout)[(size_t)(rbase + r) * N + col] = (_Float16)o;
            }
        }
    }
}

// ---------------------------------------------------------------------------
// Per (b, nh) attention; 128 threads. q/k/v fp16 in, fp32 math, o fp16 out.
// Vectorized kh staging (f16x8) + 4-lane-group parallel softmax (R12 proven).
// ---------------------------------------------------------------------------
__global__ __launch_bounds__(128) void attn_kernel(
    const _Float16* __restrict__ q, const _Float16* __restrict__ k,
    const _Float16* __restrict__ v, const float* __restrict__ bias_table,
    const int* __restrict__ cidx, const int* __restrict__ p,
    _Float16* __restrict__ obuf)
{
    const int blk = blockIdx.x;
    const int b = blk / NHEAD, nh = blk % NHEAD;
    const int tid = threadIdx.x;

    __shared__ int cI[TSEL], pI[TSEL];
    __shared__ float qal[TSEL][33];
    __shared__ float kh[NTOK][33];
    __shared__ float attnS[NTOK][33];
    __shared__ float gateS[NTOK];
    __shared__ float vs[TSEL][65];

    if (tid < TSEL) {
        cI[tid] = cidx[blk * HD2 + tid];
        pI[tid] = p[blk * TSEL + tid];
    }
    __syncthreads();

    // qal: 32x32 scalar gather (data-dependent indices)
    for (int idx = tid; idx < TSEL * HD2; idx += 128) {
        const int t = idx >> 5, j = idx & 31;
        qal[t][j] = (float)q[((size_t)(b * NTOK + pI[t])) * CDIM + nh * HDIM + cI[j]] * SCALE_Q;
    }
    // kh: 49 rows x 4 f16x8 segments (vectorized)
    for (int idx = tid; idx < NTOK * 4; idx += 128) {
        const int i = idx >> 2, seg = idx & 3;
        const f16x8 kv = *reinterpret_cast<const f16x8*>(
            &k[((size_t)(b * NTOK + i)) * C2DIM + nh * HD2 + seg * 8]);
        #pragma unroll
        for (int u = 0; u < 8; ++u) kh[i][seg * 8 + u] = (float)kv[u];
    }
    // vs: 32 rows x 8 f16x8 segments
    for (int idx = tid; idx < TSEL * 8; idx += 128) {
        const int t = idx >> 3, seg = idx & 7;
        const f16x8 vv = *reinterpret_cast<const f16x8*>(
            &v[((size_t)(b * TSEL + t)) * CDIM + nh * HDIM + seg * 8]);
        #pragma unroll
        for (int u = 0; u < 8; ++u) vs[t][seg * 8 + u] = (float)vv[u];
    }
    __syncthreads();

    // QK^T + rel-pos bias
    {
        const int t = tid & 31;
        const int pt = pI[t];
        const int pti = pt / 7, ptj = pt % 7;
        for (int i = tid >> 5; i < NTOK; i += 4) {
            const int ri = i / 7 - pti + 6;
            const int rj = i % 7 - ptj + 6;
            float a = bias_table[(ri * 13 + rj) * NHEAD + nh];
            #pragma unroll
            for (int j = 0; j < HD2; j++) a += kh[i][j] * qal[t][j];
            attnS[i][t] = a;
        }
    }
    __syncthreads();

    // group-parallel softmax + gate: 4 lanes per row, 8 elements each
    {
        const int sub = tid & 3;
        for (int row = tid >> 2; row < NTOK; row += 32) {
            float x[8];
            float m = -INFINITY, tot = 0.f;
            #pragma unroll
            for (int u = 0; u < 8; ++u) {
                x[u] = attnS[row][sub * 8 + u];
                m = fmaxf(m, x[u]);
                tot += x[u];
            }
            m = fmaxf(m, __shfl_xor(m, 1));
            m = fmaxf(m, __shfl_xor(m, 2));
            tot += __shfl_xor(tot, 1);
            tot += __shfl_xor(tot, 2);
            float s = 0.f;
            #pragma unroll
            for (int u = 0; u < 8; ++u) { x[u] = expf(x[u] - m); s += x[u]; }
            s += __shfl_xor(s, 1);
            s += __shfl_xor(s, 2);
            const float inv = 1.0f / s;
            #pragma unroll
            for (int u = 0; u < 8; ++u) attnS[row][sub * 8 + u] = x[u] * inv;
            if (sub == 0)
                gateS[row] = 1.0f / (1.0f + expf(-tot * (1.0f / 32.0f)));
        }
    }
    __syncthreads();

    // PV: thread owns 2 adjacent d columns; quarter-strided rows
    {
        const int d2 = (tid & 31) * 2;
        for (int i = tid >> 5; i < NTOK; i += 4) {
            float a0 = 0.f, a1 = 0.f;
            #pragma unroll
            for (int tt = 0; tt < TSEL; tt++) {
                const float w = attnS[i][tt];
                a0 += w * vs[tt][d2];
                a1 += w * vs[tt][d2 + 1];
            }
            const float gg = gateS[i];
            f16x2 o2 = {(_Float16)(a0 * gg), (_Float16)(a1 * gg)};
            *reinterpret_cast<f16x2*>(
                &obuf[((size_t)(b * NTOK + i)) * CDIM + nh * HDIM + d2]) = o2;
        }
    }
}

// ---------------------------------------------------------------------------
extern "C" void kernel_launch(void* const* d_in, const int* in_sizes, int n_in,
                              void* d_out, int out_size, void* d_ws, size_t ws_size,
                              hipStream_t stream)
{
    const float* x = (const float*)d_in[0];
    const float* Wq = (const float*)d_in[1];
    const float* bq = (const float*)d_in[2];
    const float* Wk = (const float*)d_in[3];
    const float* bk = (const float*)d_in[4];
    const float* Wv = (const float*)d_in[5];
    const float* bv = (const float*)d_in[6];
    const float* Wp = (const float*)d_in[7];
    const float* bp = (const float*)d_in[8];
    const float* Wc = (const float*)d_in[9];
    const float* bc = (const float*)d_in[10];
    const float* bias_table = (const float*)d_in[11];
    float* out = (float*)d_out;

    const size_t NQ = (size_t)MROWS * CDIM;
    char* wsp = (char*)d_ws;
    auto alloc = [&](size_t bytes) -> void* {
        void* pp = (void*)wsp;
        wsp += (bytes + 255) & ~(size_t)255;
        return pp;
    };

    _Float16* qbuf = (_Float16*)alloc(NQ * 2);                     // 154 MB
    _Float16* kbf = (_Float16*)alloc((size_t)MROWS * C2DIM * 2);   // 77 MB
    _Float16* vbf = (_Float16*)alloc((size_t)MVROWS * CDIM * 2);   // 100 MB
    _Float16* obf = (_Float16*)alloc(NQ * 2);                      // 154 MB
    float* rowmean = (float*)alloc((size_t)MROWS * NHEAD * 4);     // 4.8 MB
    float* psumA = (float*)alloc((size_t)BATCH * 2 * NHEAD * 64 * 4);
    float* pmaxA = (float*)alloc((size_t)BATCH * 2 * NHEAD * 64 * 4);
    _Float16* wk16 = (_Float16*)alloc((size_t)C2DIM * C2DIM * 2);
    _Float16* wv16 = (_Float16*)alloc((size_t)CDIM * CDIM * 2);
    _Float16* wp16 = (_Float16*)alloc((size_t)CDIM * CDIM * 2);
    int* cidx = (int*)alloc((size_t)BATCH * NHEAD * HD2 * 4);
    int* pidx = (int*)alloc((size_t)BATCH * NHEAD * TSEL * 4);
    if ((size_t)(wsp - (char*)d_ws) > ws_size) return;

    // 0) pre-convert post-decision weights to fp16
    wconv_kernel<<<144, 256, 0, stream>>>(Wk, wk16, C2DIM * C2DIM / 4);
    wconv_kernel<<<256, 256, 0, stream>>>(Wv, wv16, CDIM * CDIM / 4);
    wconv_kernel<<<256, 256, 0, stream>>>(Wp, wp16, CDIM * CDIM / 4);

    // 1) q = x @ Wq^T + bq (fp16x3 reg-staged, fused stats, fp16 qbuf)
    gemm_q_kernel<<<4704, 256, 0, stream>>>(
        x, Wq, bq, qbuf, rowmean, psumA, pmaxA);

    // 2) selections
    topk_kernel<<<BATCH * NHEAD, 64, 0, stream>>>(
        psumA, pmaxA, rowmean, bq, Wc, bc, cidx, pidx);

    // 3) k = gather_ch(q) @ Wk^T + bk  (fp16, BK=64)   grid 784x3 = 2352
    gemm_f16_kernel<1><<<2352, 256, 0, stream>>>(
        qbuf, wk16, bk, kbf, C2DIM, C2DIM, 294, 3, cidx);

    // 4) v = gather_tok(q) @ Wv^T + bv (fp16, BK=64)   grid 512x6 = 3072
    gemm_f16_kernel<2><<<3072, 256, 0, stream>>>(
        qbuf, wv16, bv, vbf, CDIM, CDIM, 384, 6, pidx);

    // 5) attention -> o fp16
    attn_kernel<<<BATCH * NHEAD, 128, 0, stream>>>(
        qbuf, kbf, vbf, bias_table, cidx, pidx, obf);

    // 6) out = o @ Wp^T + bp (fp16 -> fp32, BK=64)     grid 784x6 = 4704
    gemm_f16_kernel<0><<<4704, 256, 0, stream>>>(
        obf, wp16, bp, out, CDIM, CDIM, 588, 6, nullptr);
}